// Round 2
// baseline (3166.898 us; speedup 1.0000x reference)
//
#include <hip/hip_runtime.h>
#include <hip/hip_bf16.h>

#define BB 8
#define LL 1024
#define DD 512
#define NH 8
#define DH 64
#define NF 33
#define CO 7

typedef __hip_bfloat16 bf16;

__device__ __forceinline__ float b2f(bf16 v){ return __bfloat162float(v); }
__device__ __forceinline__ bf16 f2b(float v){ return __float2bfloat16(v); }

// Decide whether global float data is genuine f32 (flag=1) or packed bf16 (flag=0).
// f32 N(0,1): exponent field ~115..130. bf16-pair-as-u32: exponent field >=~240.
__global__ void sniff_kernel(const unsigned* __restrict__ x, int* __restrict__ flag){
    unsigned u = x[threadIdx.x];
    int e = (u >> 23) & 0xff;
    int sane = (e >= 32 && e <= 200) ? 1 : 0;
    unsigned long long m = __ballot(sane);
    if(threadIdx.x == 0) *flag = (__popcll(m) >= 32) ? 1 : 0;
}

// e[b,l,d] = sum_i x[b,l,i]*W[i,d] + bias[d]   (bf16 out)
__global__ __launch_bounds__(256) void embed_kernel(const void* __restrict__ xv,
                                                    const void* __restrict__ wv,
                                                    const void* __restrict__ bv,
                                                    const int* __restrict__ flag,
                                                    bf16* __restrict__ e){
    bool f32 = (*flag != 0);
    int idx = blockIdx.x*256 + threadIdx.x;       // over B*L*DD
    int d = idx & (DD-1);
    int row = idx >> 9;                           // b*L + l
    float acc;
    if(f32){
        const float* x = (const float*)xv;
        const float* w = (const float*)wv;
        const float* bias = (const float*)bv;
        acc = bias[d];
        #pragma unroll
        for(int i=0;i<7;i++) acc += x[row*7+i] * w[i*DD + d];
    }else{
        const bf16* x = (const bf16*)xv;
        const bf16* w = (const bf16*)wv;
        const bf16* bias = (const bf16*)bv;
        acc = b2f(bias[d]);
        #pragma unroll
        for(int i=0;i<7;i++) acc += b2f(x[row*7+i]) * b2f(w[i*DD + d]);
    }
    e[idx] = f2b(acc);
}

// moving-average decomp, kernel=25, pad=12, count_include_pad (always /25, zeros outside).
// accumulate: trend += tr (for summing enc+dec trends); else trend = tr.
__global__ __launch_bounds__(256) void decomp_kernel(const bf16* __restrict__ e,
                                                     bf16* __restrict__ seas,
                                                     bf16* __restrict__ trend,
                                                     int accumulate){
    int idx = blockIdx.x*256 + threadIdx.x;
    int d = idx & (DD-1);
    int l = (idx >> 9) & (LL-1);
    int b = idx >> 19;
    const bf16* eb = e + (size_t)b*(LL*DD) + d;
    int lo = l-12; if(lo<0) lo=0;
    int hi = l+12; if(hi>LL-1) hi=LL-1;
    float s = 0.f;
    for(int m=lo;m<=hi;m++) s += b2f(eb[(size_t)m*DD]);
    float tr = s*(1.f/25.f);
    float t_out = accumulate ? (tr + b2f(trend[idx])) : tr;
    trend[idx] = f2b(t_out);
    seas[idx]  = f2b(b2f(e[idx]) - tr);
}

// Per (b,l): 64-pt DFT per head of q-row and k-row, C_f = qf*conj(kf),
// corr[h][t] = sum_f scale_f*(Re C cos(th) - Im C sin(th)), th = 2*pi*f*t/1024,
// cross-head mean subtract, softmax over t, write bf16 w[bloc,h,l,t].
__global__ __launch_bounds__(256) void ac_pass1(const bf16* __restrict__ q,
                                                const bf16* __restrict__ k,
                                                bf16* __restrict__ w,
                                                int b_off){
    __shared__ float qr[DD], kr[DD];
    __shared__ float tabc[64], tabs[64];
    __shared__ float cre[NH][NF], cim[NH][NF];
    __shared__ float corr[NH][LL];
    __shared__ float meanrow[LL];
    __shared__ float red[8];
    int tid = threadIdx.x;
    int bloc = blockIdx.x >> 10;
    int b = b_off + bloc;
    int l = blockIdx.x & (LL-1);
    const bf16* qrow = q + ((size_t)b*LL + l)*DD;
    const bf16* krow = k + ((size_t)b*LL + l)*DD;
    if(tid < 64){
        float s, c;
        __sincosf(tid * (6.28318530717958647692f/64.f), &s, &c);
        tabc[tid]=c; tabs[tid]=s;
    }
    qr[tid] = b2f(qrow[tid]); qr[tid+256] = b2f(qrow[tid+256]);
    kr[tid] = b2f(krow[tid]); kr[tid+256] = b2f(krow[tid+256]);
    __syncthreads();
    // DFT over head dim (64 -> 33 bins), e^{-2*pi*i f j/64}
    for(int task = tid; task < NH*NF; task += 256){
        int h = task / NF, f = task - h*NF;
        const float* qh = qr + h*DH;
        const float* kh = kr + h*DH;
        float qre=0.f,qim=0.f,kre=0.f,kim=0.f;
        for(int j=0;j<DH;j++){
            int ix = (f*j) & 63;
            float c = tabc[ix], s = tabs[ix];
            float qv = qh[j], kv = kh[j];
            qre += qv*c; qim -= qv*s;
            kre += kv*c; kim -= kv*s;
        }
        float scale = (f==0 ? 1.f : 2.f) * (1.f/1024.f);
        cre[h][f] = (qre*kre + qim*kim)*scale;
        cim[h][f] = (qim*kre - qre*kim)*scale;
    }
    __syncthreads();
    // corr eval via incremental rotation e^{+i*2*pi*t*f/1024}
    for(int r=0;r<4;r++){
        int t = tid + 256*r;
        float sb, cb;
        __sincosf((float)t * (6.28318530717958647692f/1024.f), &sb, &cb);
        float cr = 1.f, ci = 0.f;
        float acc[NH];
        #pragma unroll
        for(int h=0;h<NH;h++) acc[h] = cre[h][0];
        for(int f=1;f<NF;f++){
            float nr = cr*cb - ci*sb;
            float ni = cr*sb + ci*cb;
            cr = nr; ci = ni;
            #pragma unroll
            for(int h=0;h<NH;h++) acc[h] += cre[h][f]*cr - cim[h][f]*ci;
        }
        float m = 0.f;
        #pragma unroll
        for(int h=0;h<NH;h++){ corr[h][t] = acc[h]; m += acc[h]; }
        meanrow[t] = m * 0.125f;
    }
    __syncthreads();
    // per-head softmax over t (minus cross-head mean)
    int wave = tid >> 6, lane = tid & 63;
    for(int h=0; h<NH; h++){
        float mx = -1e30f;
        for(int t=tid; t<LL; t+=256){ float v = corr[h][t]-meanrow[t]; mx = fmaxf(mx,v); }
        for(int off=32;off;off>>=1) mx = fmaxf(mx, __shfl_down(mx, off, 64));
        if(lane==0) red[wave] = mx;
        __syncthreads();
        mx = fmaxf(fmaxf(red[0],red[1]),fmaxf(red[2],red[3]));
        float sm = 0.f;
        for(int t=tid; t<LL; t+=256){
            float e = __expf(corr[h][t]-meanrow[t]-mx);
            corr[h][t]=e; sm += e;
        }
        for(int off=32;off;off>>=1) sm += __shfl_down(sm, off, 64);
        if(lane==0) red[4+wave] = sm;
        __syncthreads();
        sm = red[4]+red[5]+red[6]+red[7];
        float inv = 1.f/sm;
        bf16* wrow = w + (((size_t)(bloc*NH+h)*LL + l) * LL);
        for(int t=tid; t<LL; t+=256) wrow[t] = f2b(corr[h][t]*inv);
        __syncthreads();
    }
}

// V[b,h,i,c] = sum_j w[bloc,h,j,i]*v[b,j,h*64+c]; scatter-write per the
// torch permute/reshape: dst[b][c*8192 + h*1024 + i]
__global__ __launch_bounds__(256) void ac_pass2(const bf16* __restrict__ w,
                                                const bf16* __restrict__ v,
                                                bf16* __restrict__ dst,
                                                int b_off){
    int it = blockIdx.x & 15;
    int h  = (blockIdx.x >> 4) & 7;
    int bloc = blockIdx.x >> 7;
    int b = b_off + bloc;
    int i0 = it*64;
    __shared__ float wt[64][65];
    __shared__ float vt[64][65];
    int tid = threadIdx.x;
    int ti = tid & 15, tc = tid >> 4;
    float acc[4][4] = {};
    const bf16* wbase = w + ((size_t)(bloc*NH+h)*LL)*LL + i0;
    const bf16* vbase = v + (size_t)b*LL*DD + h*DH;
    for(int j0=0; j0<LL; j0+=64){
        #pragma unroll
        for(int r=0;r<16;r++){
            int ix = tid + r*256;
            int jj = ix >> 6, ii = ix & 63;
            wt[jj][ii] = b2f(wbase[(size_t)(j0+jj)*LL + ii]);
            vt[jj][ii] = b2f(vbase[(size_t)(j0+jj)*DD + ii]);
        }
        __syncthreads();
        for(int jj=0;jj<64;jj++){
            float wv[4], vv[4];
            #pragma unroll
            for(int a=0;a<4;a++) wv[a] = wt[jj][ti*4+a];
            #pragma unroll
            for(int c=0;c<4;c++) vv[c] = vt[jj][tc*4+c];
            #pragma unroll
            for(int a=0;a<4;a++)
                #pragma unroll
                for(int c=0;c<4;c++) acc[a][c] += wv[a]*vv[c];
        }
        __syncthreads();
    }
    bf16* db = dst + (size_t)b*LL*DD;
    #pragma unroll
    for(int c=0;c<4;c++){
        int dd = tc*4+c;
        #pragma unroll
        for(int a=0;a<4;a++){
            int i = i0 + ti*4 + a;
            db[(size_t)dd*8192 + h*1024 + i] = f2b(acc[a][c]);
        }
    }
}

// out = (seas + trend_sum) @ proj_w + proj_b  (dtype per flag)
__global__ __launch_bounds__(64) void final_kernel(const bf16* __restrict__ s,
                                                   const bf16* __restrict__ t,
                                                   const void* __restrict__ pwv,
                                                   const void* __restrict__ pbv,
                                                   const int* __restrict__ flag,
                                                   void* __restrict__ outv){
    bool f32 = (*flag != 0);
    int row = blockIdx.x;   // b*L + l
    int lane = threadIdx.x;
    const bf16* sr = s + (size_t)row*DD;
    const bf16* tr = t + (size_t)row*DD;
    float acc[CO] = {};
    for(int j=lane; j<DD; j+=64){
        float dv = b2f(sr[j]) + b2f(tr[j]);
        if(f32){
            const float* pw = (const float*)pwv;
            #pragma unroll
            for(int c=0;c<CO;c++) acc[c] += dv * pw[j*CO + c];
        }else{
            const bf16* pw = (const bf16*)pwv;
            #pragma unroll
            for(int c=0;c<CO;c++) acc[c] += dv * b2f(pw[j*CO + c]);
        }
    }
    #pragma unroll
    for(int c=0;c<CO;c++){
        float vsum = acc[c];
        for(int off=32;off;off>>=1) vsum += __shfl_down(vsum,off,64);
        if(lane==0){
            float bias = f32 ? ((const float*)pbv)[c] : b2f(((const bf16*)pbv)[c]);
            float o = vsum + bias;
            if(f32) ((float*)outv)[(size_t)row*CO + c] = o;
            else    ((bf16*)outv)[(size_t)row*CO + c] = f2b(o);
        }
    }
}

extern "C" void kernel_launch(void* const* d_in, const int* in_sizes, int n_in,
                              void* d_out, int out_size, void* d_ws, size_t ws_size,
                              hipStream_t stream){
    const void* x_enc  = d_in[0];
    const void* x_dec  = d_in[2];
    const void* enc_w  = d_in[4];
    const void* enc_b  = d_in[5];
    const void* dec_w  = d_in[6];
    const void* dec_b  = d_in[7];
    const void* proj_w = d_in[8];
    const void* proj_b = d_in[9];

    // workspace layout: [flag 1KiB][A 8MiB][Bf 8MiB][C 8MiB][T 8MiB][W 16*bsz MiB]
    int*  flag = (int*)d_ws;
    const size_t NE = (size_t)BB*LL*DD;           // 4M elems per state buffer
    bf16* A  = (bf16*)((char*)d_ws + 1024);
    bf16* Bf = A  + NE;
    bf16* C  = Bf + NE;
    bf16* T  = C  + NE;
    bf16* W  = T  + NE;

    size_t used = 1024 + 4*NE*sizeof(bf16);
    size_t avail = (ws_size > used) ? (ws_size - used) : 0;
    int bsz = 1;
    for(int cand : {8,4,2}){
        if((size_t)cand * NH * (size_t)LL * LL * sizeof(bf16) <= avail){ bsz = cand; break; }
    }

    sniff_kernel<<<1,64,0,stream>>>((const unsigned*)x_enc, flag);

    auto autocorr = [&](const bf16* q, const bf16* kv, bf16* dst){
        for(int b0 = 0; b0 < BB; b0 += bsz){
            ac_pass1<<<bsz*LL, 256, 0, stream>>>(q, kv, W, b0);
            ac_pass2<<<bsz*NH*16, 256, 0, stream>>>(W, kv, dst, b0);
        }
    };

    // encoder: embed -> decomp -> 2x self-autocorr
    embed_kernel<<<16384,256,0,stream>>>(x_enc, enc_w, enc_b, flag, Bf);
    decomp_kernel<<<16384,256,0,stream>>>(Bf, A, T, 0);   // A=enc_seasonal, T=enc_trend
    autocorr(A, A, Bf);      // layer 1 -> Bf
    autocorr(Bf, Bf, A);     // layer 2 -> A (= enc_seasonal out)

    // decoder: embed -> decomp(trend accumulates into T) -> cross autocorr
    embed_kernel<<<16384,256,0,stream>>>(x_dec, dec_w, dec_b, flag, C);
    decomp_kernel<<<16384,256,0,stream>>>(C, Bf, T, 1);   // Bf=dec_seasonal, T+=dec_trend
    autocorr(Bf, A, C);      // q=dec seasonal, k=v=enc_seasonal -> C

    // out = (C + T) @ proj_w + proj_b
    final_kernel<<<BB*LL,64,0,stream>>>(C, T, proj_w, proj_b, flag, d_out);
}

// Round 3
// 995.389 us; speedup vs baseline: 3.1816x; 3.1816x over previous
//
#include <hip/hip_runtime.h>
#include <hip/hip_bf16.h>

#define BB 8
#define LL 1024
#define DD 512
#define NH 8
#define DH 64
#define NF 33
#define CO 7
#define GK 96          // padded K for corr GEMM (66 real + 30 zero)

typedef __hip_bfloat16 bf16;
typedef __attribute__((ext_vector_type(8))) short short8;
typedef __attribute__((ext_vector_type(4))) float floatx4;
typedef __attribute__((ext_vector_type(4))) unsigned short ushort4v;

__device__ __forceinline__ float b2f(bf16 v){ return __bfloat162float(v); }
__device__ __forceinline__ bf16 f2b(float v){ return __float2bfloat16(v); }
__device__ __forceinline__ float bu2f(unsigned short u){
    union{unsigned i; float f;} x; x.i = ((unsigned)u)<<16; return x.f;
}
__device__ __forceinline__ unsigned short f2bu(float v){
    bf16 h = f2b(v); return *(unsigned short*)&h;
}

// Decide whether global float data is genuine f32 (flag=1) or packed bf16 (flag=0).
__global__ void sniff_kernel(const unsigned* __restrict__ x, int* __restrict__ flag){
    unsigned u = x[threadIdx.x];
    int e = (u >> 23) & 0xff;
    int sane = (e >= 32 && e <= 200) ? 1 : 0;
    unsigned long long m = __ballot(sane);
    if(threadIdx.x == 0) *flag = (__popcll(m) >= 32) ? 1 : 0;
}

// e[b,l,d] = sum_i x[b,l,i]*W[i,d] + bias[d]   (bf16 out)
__global__ __launch_bounds__(256) void embed_kernel(const void* __restrict__ xv,
                                                    const void* __restrict__ wv,
                                                    const void* __restrict__ bv,
                                                    const int* __restrict__ flag,
                                                    bf16* __restrict__ e){
    bool f32 = (*flag != 0);
    int idx = blockIdx.x*256 + threadIdx.x;
    int d = idx & (DD-1);
    int row = idx >> 9;
    float acc;
    if(f32){
        const float* x = (const float*)xv;
        const float* w = (const float*)wv;
        const float* bias = (const float*)bv;
        acc = bias[d];
        #pragma unroll
        for(int i=0;i<7;i++) acc += x[row*7+i] * w[i*DD + d];
    }else{
        const bf16* x = (const bf16*)xv;
        const bf16* w = (const bf16*)wv;
        const bf16* bias = (const bf16*)bv;
        acc = b2f(bias[d]);
        #pragma unroll
        for(int i=0;i<7;i++) acc += b2f(x[row*7+i]) * b2f(w[i*DD + d]);
    }
    e[idx] = f2b(acc);
}

// moving-average decomp, kernel=25, pad=12, count_include_pad.
__global__ __launch_bounds__(256) void decomp_kernel(const bf16* __restrict__ e,
                                                     bf16* __restrict__ seas,
                                                     bf16* __restrict__ trend,
                                                     int accumulate){
    int idx = blockIdx.x*256 + threadIdx.x;
    int d = idx & (DD-1);
    int l = (idx >> 9) & (LL-1);
    int b = idx >> 19;
    const bf16* eb = e + (size_t)b*(LL*DD) + d;
    int lo = l-12; if(lo<0) lo=0;
    int hi = l+12; if(hi>LL-1) hi=LL-1;
    float s = 0.f;
    for(int m=lo;m<=hi;m++) s += b2f(eb[(size_t)m*DD]);
    float tr = s*(1.f/25.f);
    float t_out = accumulate ? (tr + b2f(trend[idx])) : tr;
    trend[idx] = f2b(t_out);
    seas[idx]  = f2b(b2f(e[idx]) - tr);
}

// trig table Tg[t][k]: k=2f -> cos(2*pi*f*t/1024), k=2f+1 -> sin(...), k>=66 -> 0
__global__ __launch_bounds__(128) void trig_init(bf16* __restrict__ Tg){
    int t = blockIdx.x, k = threadIdx.x;
    if(k >= GK) return;
    float v = 0.f;
    if(k < 2*NF){
        int f = k >> 1;
        int ph = (f*t) & 1023;               // exact periodicity reduction
        float s, c;
        __sincosf((float)ph * (6.28318530717958647692f/1024.f), &s, &c);
        v = (k & 1) ? s : c;
    }
    Tg[(size_t)t*GK + k] = f2b(v);
}

// Per (b,l): 64-pt DFT per head of q-row and k-row (incremental rotation),
// C_f = qf*conj(kf); write A[m=h*1024+l][2f]=Re(C)*scale, [2f+1]=-Im(C)*scale, pad 0.
__global__ __launch_bounds__(256) void dft_kernel(const bf16* __restrict__ q,
                                                  const bf16* __restrict__ k,
                                                  bf16* __restrict__ Ab,
                                                  int b_off){
    __shared__ float qr[DD], kr[DD];
    int tid = threadIdx.x;
    int bloc = blockIdx.x >> 10;
    int b = b_off + bloc;
    int l = blockIdx.x & (LL-1);
    const bf16* qrow = q + ((size_t)b*LL + l)*DD;
    const bf16* krow = k + ((size_t)b*LL + l)*DD;
    qr[tid] = b2f(qrow[tid]); qr[tid+256] = b2f(qrow[tid+256]);
    kr[tid] = b2f(krow[tid]); kr[tid+256] = b2f(krow[tid+256]);
    __syncthreads();
    for(int task = tid; task < NH*NF; task += 256){
        int h = task / NF, f = task - h*NF;
        const float* qh = qr + h*DH;
        const float* kh = kr + h*DH;
        float sb, cb;
        __sincosf((float)f * (6.28318530717958647692f/64.f), &sb, &cb);
        float cr = 1.f, ci = 0.f;   // e^{-i*2*pi*f*j/64}
        float qre=0.f,qim=0.f,kre=0.f,kim=0.f;
        for(int j=0;j<DH;j++){
            float qv = qh[j], kv = kh[j];
            qre += qv*cr; qim += qv*ci;
            kre += kv*cr; kim += kv*ci;
            float nr = cr*cb + ci*sb;
            float ni = ci*cb - cr*sb;
            cr = nr; ci = ni;
        }
        float scale = (f==0 ? 1.f : 2.f) * (1.f/1024.f);
        size_t rowb = ((size_t)bloc*(NH*LL) + h*LL + l)*GK;
        Ab[rowb + 2*f]   = f2b((qre*kre + qim*kim)*scale);
        Ab[rowb + 2*f+1] = f2b(-(qim*kre - qre*kim)*scale);
    }
    // zero pad k=66..95
    for(int idx = tid; idx < NH*(GK-2*NF); idx += 256){
        int h = idx / (GK-2*NF), kk = 2*NF + idx % (GK-2*NF);
        Ab[((size_t)bloc*(NH*LL) + h*LL + l)*GK + kk] = f2b(0.f);
    }
}

// corr GEMM: W[bloc][m][t] = sum_k Ab[bloc][m][k] * Tg[t][k]; M=8192,N=1024,K=96.
// 128x128 tile, 4 waves, 16x16x32 bf16 MFMA.
__global__ __launch_bounds__(256) void corr_gemm(const bf16* __restrict__ Ab,
                                                 const bf16* __restrict__ Tg,
                                                 bf16* __restrict__ Wb){
    __shared__ __align__(16) short As[128][40];
    __shared__ __align__(16) short Bs[128][40];
    int tid = threadIdx.x;
    int bm0 = blockIdx.x * 128;
    int bn0 = blockIdx.y * 128;
    int bloc = blockIdx.z;
    const short* Abase = (const short*)(Ab + ((size_t)bloc*(NH*LL) + bm0)*GK);
    const short* Bbase = (const short*)(Tg + (size_t)bn0*GK);
    int wv = tid >> 6, lane = tid & 63;
    int wm = (wv >> 1)*64, wn = (wv & 1)*64;
    floatx4 acc[4][4] = {};
    int sr = tid >> 2, sc = (tid & 3)*8;
    int kb = (lane>>4)*8;
    int rr = lane & 15;
    for(int k0=0; k0<GK; k0+=32){
        #pragma unroll
        for(int half=0; half<2; half++){
            int row = sr + half*64;
            *(short8*)&As[row][sc] = *(const short8*)&Abase[(size_t)row*GK + k0 + sc];
            *(short8*)&Bs[row][sc] = *(const short8*)&Bbase[(size_t)row*GK + k0 + sc];
        }
        __syncthreads();
        short8 af[4], bfr[4];
        #pragma unroll
        for(int mt=0;mt<4;mt++) af[mt]  = *(const short8*)&As[wm + mt*16 + rr][kb];
        #pragma unroll
        for(int nt=0;nt<4;nt++) bfr[nt] = *(const short8*)&Bs[wn + nt*16 + rr][kb];
        #pragma unroll
        for(int mt=0;mt<4;mt++)
            #pragma unroll
            for(int nt=0;nt<4;nt++)
                acc[mt][nt] = __builtin_amdgcn_mfma_f32_16x16x32_bf16(af[mt], bfr[nt], acc[mt][nt], 0,0,0);
        __syncthreads();
    }
    // C/D: col = lane&15, row = (lane>>4)*4 + r
    int qrow = (lane>>4)*4, qcol = lane & 15;
    #pragma unroll
    for(int mt=0;mt<4;mt++){
        #pragma unroll
        for(int nt=0;nt<4;nt++){
            int t = bn0 + wn + nt*16 + qcol;
            #pragma unroll
            for(int r=0;r<4;r++){
                int m = bm0 + wm + mt*16 + qrow + r;
                Wb[((size_t)bloc*(NH*LL) + m)*LL + t] = f2b(acc[mt][nt][r]);
            }
        }
    }
}

// in-place: per (bloc,l): mean over h, per-head softmax over t. W[bloc][h*1024+l][t]
__global__ __launch_bounds__(256) void softmax_kernel(bf16* __restrict__ W){
    __shared__ float corr[NH][LL];
    __shared__ float meanrow[LL];
    int tid = threadIdx.x;
    int bloc = blockIdx.x >> 10;
    int l = blockIdx.x & (LL-1);
    int t0 = tid*4;
    // load + mean
    float msum[4] = {};
    #pragma unroll
    for(int h=0;h<NH;h++){
        const ushort4v u = *(const ushort4v*)(W + ((size_t)bloc*(NH*LL) + h*LL + l)*LL + t0);
        float v0=bu2f(u.x), v1=bu2f(u.y), v2=bu2f(u.z), v3=bu2f(u.w);
        corr[h][t0]=v0; corr[h][t0+1]=v1; corr[h][t0+2]=v2; corr[h][t0+3]=v3;
        msum[0]+=v0; msum[1]+=v1; msum[2]+=v2; msum[3]+=v3;
    }
    #pragma unroll
    for(int j=0;j<4;j++) meanrow[t0+j] = msum[j]*0.125f;
    __syncthreads();
    // per-wave softmax: wave w handles heads 2w, 2w+1; only wave-level shuffles
    int wv = tid >> 6, lane = tid & 63;
    #pragma unroll
    for(int hh=0; hh<2; hh++){
        int h = wv*2 + hh;
        float v[16];
        float mx = -1e30f;
        #pragma unroll
        for(int i=0;i<16;i++){
            int t = lane + 64*i;
            v[i] = corr[h][t] - meanrow[t];
            mx = fmaxf(mx, v[i]);
        }
        for(int off=32;off;off>>=1) mx = fmaxf(mx, __shfl_xor(mx, off, 64));
        float sm = 0.f;
        #pragma unroll
        for(int i=0;i<16;i++){ v[i] = __expf(v[i]-mx); sm += v[i]; }
        for(int off=32;off;off>>=1) sm += __shfl_xor(sm, off, 64);
        float inv = 1.f/sm;
        #pragma unroll
        for(int i=0;i<16;i++) corr[h][lane + 64*i] = v[i]*inv;
    }
    __syncthreads();
    // store
    #pragma unroll
    for(int h=0;h<NH;h++){
        ushort4v u;
        u.x = f2bu(corr[h][t0]);   u.y = f2bu(corr[h][t0+1]);
        u.z = f2bu(corr[h][t0+2]); u.w = f2bu(corr[h][t0+3]);
        *(ushort4v*)(W + ((size_t)bloc*(NH*LL) + h*LL + l)*LL + t0) = u;
    }
}

// V[b,h,i,c] = sum_j w[bloc,h,j,i]*v[b,j,h*64+c]; dst[b][c*8192 + h*1024 + i]
__global__ __launch_bounds__(256) void ac_pass2(const bf16* __restrict__ w,
                                                const bf16* __restrict__ v,
                                                bf16* __restrict__ dst,
                                                int b_off){
    int it = blockIdx.x & 15;
    int h  = (blockIdx.x >> 4) & 7;
    int bloc = blockIdx.x >> 7;
    int b = b_off + bloc;
    int i0 = it*64;
    __shared__ float wt[64][65];
    __shared__ float vt[64][65];
    int tid = threadIdx.x;
    int ti = tid & 15, tc = tid >> 4;
    float acc[4][4] = {};
    const bf16* wbase = w + ((size_t)(bloc*NH+h)*LL)*LL + i0;
    const bf16* vbase = v + (size_t)b*LL*DD + h*DH;
    for(int j0=0; j0<LL; j0+=64){
        #pragma unroll
        for(int r=0;r<16;r++){
            int ix = tid + r*256;
            int jj = ix >> 6, ii = ix & 63;
            wt[jj][ii] = b2f(wbase[(size_t)(j0+jj)*LL + ii]);
            vt[jj][ii] = b2f(vbase[(size_t)(j0+jj)*DD + ii]);
        }
        __syncthreads();
        for(int jj=0;jj<64;jj++){
            float wv[4], vv[4];
            #pragma unroll
            for(int a=0;a<4;a++) wv[a] = wt[jj][ti*4+a];
            #pragma unroll
            for(int c=0;c<4;c++) vv[c] = vt[jj][tc*4+c];
            #pragma unroll
            for(int a=0;a<4;a++)
                #pragma unroll
                for(int c=0;c<4;c++) acc[a][c] += wv[a]*vv[c];
        }
        __syncthreads();
    }
    bf16* db = dst + (size_t)b*LL*DD;
    #pragma unroll
    for(int c=0;c<4;c++){
        int dd = tc*4+c;
        #pragma unroll
        for(int a=0;a<4;a++){
            int i = i0 + ti*4 + a;
            db[(size_t)dd*8192 + h*1024 + i] = f2b(acc[a][c]);
        }
    }
}

// out = (seas + trend_sum) @ proj_w + proj_b  (dtype per flag)
__global__ __launch_bounds__(64) void final_kernel(const bf16* __restrict__ s,
                                                   const bf16* __restrict__ t,
                                                   const void* __restrict__ pwv,
                                                   const void* __restrict__ pbv,
                                                   const int* __restrict__ flag,
                                                   void* __restrict__ outv){
    bool f32 = (*flag != 0);
    int row = blockIdx.x;
    int lane = threadIdx.x;
    const bf16* sr = s + (size_t)row*DD;
    const bf16* tr = t + (size_t)row*DD;
    float acc[CO] = {};
    for(int j=lane; j<DD; j+=64){
        float dv = b2f(sr[j]) + b2f(tr[j]);
        if(f32){
            const float* pw = (const float*)pwv;
            #pragma unroll
            for(int c=0;c<CO;c++) acc[c] += dv * pw[j*CO + c];
        }else{
            const bf16* pw = (const bf16*)pwv;
            #pragma unroll
            for(int c=0;c<CO;c++) acc[c] += dv * b2f(pw[j*CO + c]);
        }
    }
    #pragma unroll
    for(int c=0;c<CO;c++){
        float vsum = acc[c];
        for(int off=32;off;off>>=1) vsum += __shfl_down(vsum,off,64);
        if(lane==0){
            float bias = f32 ? ((const float*)pbv)[c] : b2f(((const bf16*)pbv)[c]);
            float o = vsum + bias;
            if(f32) ((float*)outv)[(size_t)row*CO + c] = o;
            else    ((bf16*)outv)[(size_t)row*CO + c] = f2b(o);
        }
    }
}

extern "C" void kernel_launch(void* const* d_in, const int* in_sizes, int n_in,
                              void* d_out, int out_size, void* d_ws, size_t ws_size,
                              hipStream_t stream){
    const void* x_enc  = d_in[0];
    const void* x_dec  = d_in[2];
    const void* enc_w  = d_in[4];
    const void* enc_b  = d_in[5];
    const void* dec_w  = d_in[6];
    const void* dec_b  = d_in[7];
    const void* proj_w = d_in[8];
    const void* proj_b = d_in[9];

    int*  flag = (int*)d_ws;
    const size_t NE = (size_t)BB*LL*DD;          // 4M elems per state buffer
    bf16* A  = (bf16*)((char*)d_ws + 1024);
    bf16* Bf = A  + NE;
    bf16* C  = Bf + NE;
    bf16* T  = C  + NE;
    bf16* Tg = T  + NE;                          // 1024*96 bf16 trig table
    bf16* Ab = Tg + (size_t)LL*GK;               // per-batch spectra

    const size_t AB_ELEMS = (size_t)NH*LL*GK;    // per bloc
    const size_t W_ELEMS  = (size_t)NH*LL*LL;    // per bloc
    size_t base = 1024 + 4*NE*sizeof(bf16) + (size_t)LL*GK*sizeof(bf16);
    int bsz = 1;
    for(int cand : {8,4,2}){
        if(base + (size_t)cand*(AB_ELEMS + W_ELEMS)*sizeof(bf16) <= ws_size){ bsz = cand; break; }
    }
    bf16* W = Ab + (size_t)bsz*AB_ELEMS;

    sniff_kernel<<<1,64,0,stream>>>((const unsigned*)x_enc, flag);
    trig_init<<<LL,128,0,stream>>>(Tg);

    auto autocorr = [&](const bf16* q, const bf16* kv, bf16* dst){
        for(int b0 = 0; b0 < BB; b0 += bsz){
            dft_kernel<<<bsz*LL, 256, 0, stream>>>(q, kv, Ab, b0);
            corr_gemm<<<dim3(64, 8, bsz), 256, 0, stream>>>(Ab, Tg, W);
            softmax_kernel<<<bsz*LL, 256, 0, stream>>>(W);
            ac_pass2<<<bsz*NH*16, 256, 0, stream>>>(W, kv, dst, b0);
        }
    };

    // encoder: embed -> decomp -> 2x self-autocorr
    embed_kernel<<<16384,256,0,stream>>>(x_enc, enc_w, enc_b, flag, Bf);
    decomp_kernel<<<16384,256,0,stream>>>(Bf, A, T, 0);   // A=enc_seasonal, T=enc_trend
    autocorr(A, A, Bf);      // layer 1 -> Bf
    autocorr(Bf, Bf, A);     // layer 2 -> A (= enc_seasonal out)

    // decoder: embed -> decomp(trend accumulates) -> cross autocorr
    embed_kernel<<<16384,256,0,stream>>>(x_dec, dec_w, dec_b, flag, C);
    decomp_kernel<<<16384,256,0,stream>>>(C, Bf, T, 1);   // Bf=dec_seasonal, T+=dec_trend
    autocorr(Bf, A, C);      // q=dec seasonal, k=v=enc_seasonal -> C

    // out = (C + T) @ proj_w + proj_b
    final_kernel<<<BB*LL,64,0,stream>>>(C, T, proj_w, proj_b, flag, d_out);
}

// Round 4
// 610.891 us; speedup vs baseline: 5.1841x; 1.6294x over previous
//
#include <hip/hip_runtime.h>
#include <hip/hip_bf16.h>

#define BB 8
#define LL 1024
#define DD 512
#define NH 8
#define DH 64
#define CO 7
#define GK 64          // K for corr GEMM: f=1..32, (re,im) pairs; f=0 dropped (softmax-invariant)

typedef __hip_bfloat16 bf16;
typedef __attribute__((ext_vector_type(8))) short short8;
typedef __attribute__((ext_vector_type(4))) float floatx4;
typedef __attribute__((ext_vector_type(4))) unsigned short ushort4v;

__device__ __forceinline__ float b2f(bf16 v){ return __bfloat162float(v); }
__device__ __forceinline__ bf16 f2b(float v){ return __float2bfloat16(v); }
__device__ __forceinline__ float bu2f(unsigned short u){
    union{unsigned i; float f;} x; x.i = ((unsigned)u)<<16; return x.f;
}
__device__ __forceinline__ unsigned short f2bu(float v){
    bf16 h = f2b(v); return *(unsigned short*)&h;
}

// Decide whether global float data is genuine f32 (flag=1) or packed bf16 (flag=0).
__global__ void sniff_kernel(const unsigned* __restrict__ x, int* __restrict__ flag){
    unsigned u = x[threadIdx.x];
    int e = (u >> 23) & 0xff;
    int sane = (e >= 32 && e <= 200) ? 1 : 0;
    unsigned long long m = __ballot(sane);
    if(threadIdx.x == 0) *flag = (__popcll(m) >= 32) ? 1 : 0;
}

// e[b,l,d] = sum_i x[b,l,i]*W[i,d] + bias[d]   (bf16 out)
__global__ __launch_bounds__(256) void embed_kernel(const void* __restrict__ xv,
                                                    const void* __restrict__ wv,
                                                    const void* __restrict__ bv,
                                                    const int* __restrict__ flag,
                                                    bf16* __restrict__ e){
    bool f32 = (*flag != 0);
    int idx = blockIdx.x*256 + threadIdx.x;
    int d = idx & (DD-1);
    int row = idx >> 9;
    float acc;
    if(f32){
        const float* x = (const float*)xv;
        const float* w = (const float*)wv;
        const float* bias = (const float*)bv;
        acc = bias[d];
        #pragma unroll
        for(int i=0;i<7;i++) acc += x[row*7+i] * w[i*DD + d];
    }else{
        const bf16* x = (const bf16*)xv;
        const bf16* w = (const bf16*)wv;
        const bf16* bias = (const bf16*)bv;
        acc = b2f(bias[d]);
        #pragma unroll
        for(int i=0;i<7;i++) acc += b2f(x[row*7+i]) * b2f(w[i*DD + d]);
    }
    e[idx] = f2b(acc);
}

// moving-average decomp, kernel=25, pad=12, count_include_pad.
__global__ __launch_bounds__(256) void decomp_kernel(const bf16* __restrict__ e,
                                                     bf16* __restrict__ seas,
                                                     bf16* __restrict__ trend,
                                                     int accumulate){
    int idx = blockIdx.x*256 + threadIdx.x;
    int d = idx & (DD-1);
    int l = (idx >> 9) & (LL-1);
    int b = idx >> 19;
    const bf16* eb = e + (size_t)b*(LL*DD) + d;
    int lo = l-12; if(lo<0) lo=0;
    int hi = l+12; if(hi>LL-1) hi=LL-1;
    float s = 0.f;
    for(int m=lo;m<=hi;m++) s += b2f(eb[(size_t)m*DD]);
    float tr = s*(1.f/25.f);
    float t_out = accumulate ? (tr + b2f(trend[idx])) : tr;
    trend[idx] = f2b(t_out);
    seas[idx]  = f2b(b2f(e[idx]) - tr);
}

// trig table Tg[t][k]: k=2(f-1) -> cos(2*pi*f*t/1024), k=2(f-1)+1 -> sin, f=1..32
__global__ __launch_bounds__(64) void trig_init(bf16* __restrict__ Tg){
    int t = blockIdx.x, k = threadIdx.x;
    int f = (k >> 1) + 1;
    int ph = (f*t) & 1023;
    float s, c;
    __sincosf((float)ph * (6.28318530717958647692f/1024.f), &s, &c);
    Tg[(size_t)t*GK + k] = f2b((k & 1) ? s : c);
}

// Per (b,l): 64-pt DFT per head of q-row and k-row (incremental rotation),
// C_f = qf*conj(kf), f=1..32; A[m=h*1024+l][2(f-1)]=Re*s, [2(f-1)+1]=-Im*s.
__global__ __launch_bounds__(256) void dft_kernel(const bf16* __restrict__ q,
                                                  const bf16* __restrict__ k,
                                                  bf16* __restrict__ Ab,
                                                  int b_off){
    __shared__ float qr[DD], kr[DD];
    int tid = threadIdx.x;
    int bloc = blockIdx.x >> 10;
    int b = b_off + bloc;
    int l = blockIdx.x & (LL-1);
    const bf16* qrow = q + ((size_t)b*LL + l)*DD;
    const bf16* krow = k + ((size_t)b*LL + l)*DD;
    qr[tid] = b2f(qrow[tid]); qr[tid+256] = b2f(qrow[tid+256]);
    kr[tid] = b2f(krow[tid]); kr[tid+256] = b2f(krow[tid+256]);
    __syncthreads();
    int h = tid >> 5, f = (tid & 31) + 1;     // exactly 256 tasks
    const float* qh = qr + h*DH;
    const float* kh = kr + h*DH;
    float sb, cb;
    __sincosf((float)f * (6.28318530717958647692f/64.f), &sb, &cb);
    float cr = 1.f, ci = 0.f;   // e^{-i*2*pi*f*j/64}
    float qre=0.f,qim=0.f,kre=0.f,kim=0.f;
    for(int j=0;j<DH;j++){
        float qv = qh[j], kv = kh[j];
        qre += qv*cr; qim += qv*ci;
        kre += kv*cr; kim += kv*ci;
        float nr = cr*cb + ci*sb;
        float ni = ci*cb - cr*sb;
        cr = nr; ci = ni;
    }
    const float scale = 1.f/512.f;            // 2/1024
    size_t rowb = ((size_t)bloc*(NH*LL) + h*LL + l)*GK;
    Ab[rowb + 2*(f-1)]   = f2b((qre*kre + qim*kim)*scale);
    Ab[rowb + 2*(f-1)+1] = f2b(-(qim*kre - qre*kim)*scale);
}

// corr GEMM: W[bloc][m][t] = sum_k Ab[bloc][m][k] * Tg[t][k]; M=8192,N=1024,K=64.
__global__ __launch_bounds__(256) void corr_gemm(const bf16* __restrict__ Ab,
                                                 const bf16* __restrict__ Tg,
                                                 bf16* __restrict__ Wb){
    __shared__ __align__(16) short As[128][40];
    __shared__ __align__(16) short Bs[128][40];
    int tid = threadIdx.x;
    int bm0 = blockIdx.x * 128;
    int bn0 = blockIdx.y * 128;
    int bloc = blockIdx.z;
    const short* Abase = (const short*)(Ab + ((size_t)bloc*(NH*LL) + bm0)*GK);
    const short* Bbase = (const short*)(Tg + (size_t)bn0*GK);
    int wv = tid >> 6, lane = tid & 63;
    int wm = (wv >> 1)*64, wn = (wv & 1)*64;
    floatx4 acc[4][4] = {};
    int sr = tid >> 2, sc = (tid & 3)*8;
    int kb = (lane>>4)*8;
    int rr = lane & 15;
    for(int k0=0; k0<GK; k0+=32){
        #pragma unroll
        for(int half=0; half<2; half++){
            int row = sr + half*64;
            *(short8*)&As[row][sc] = *(const short8*)&Abase[(size_t)row*GK + k0 + sc];
            *(short8*)&Bs[row][sc] = *(const short8*)&Bbase[(size_t)row*GK + k0 + sc];
        }
        __syncthreads();
        short8 af[4], bfr[4];
        #pragma unroll
        for(int mt=0;mt<4;mt++) af[mt]  = *(const short8*)&As[wm + mt*16 + rr][kb];
        #pragma unroll
        for(int nt=0;nt<4;nt++) bfr[nt] = *(const short8*)&Bs[wn + nt*16 + rr][kb];
        #pragma unroll
        for(int mt=0;mt<4;mt++)
            #pragma unroll
            for(int nt=0;nt<4;nt++)
                acc[mt][nt] = __builtin_amdgcn_mfma_f32_16x16x32_bf16(af[mt], bfr[nt], acc[mt][nt], 0,0,0);
        __syncthreads();
    }
    int qrow = (lane>>4)*4, qcol = lane & 15;
    #pragma unroll
    for(int mt=0;mt<4;mt++){
        #pragma unroll
        for(int nt=0;nt<4;nt++){
            int t = bn0 + wn + nt*16 + qcol;
            #pragma unroll
            for(int r=0;r<4;r++){
                int m = bm0 + wm + mt*16 + qrow + r;
                Wb[((size_t)bloc*(NH*LL) + m)*LL + t] = f2b(acc[mt][nt][r]);
            }
        }
    }
}

// in-place: per (bloc,l): mean over h, per-head softmax over t. W[bloc][h*1024+l][t]
__global__ __launch_bounds__(256) void softmax_kernel(bf16* __restrict__ W){
    __shared__ float corr[NH][LL];
    __shared__ float meanrow[LL];
    int tid = threadIdx.x;
    int bloc = blockIdx.x >> 10;
    int l = blockIdx.x & (LL-1);
    int t0 = tid*4;
    float msum[4] = {};
    #pragma unroll
    for(int h=0;h<NH;h++){
        const ushort4v u = *(const ushort4v*)(W + ((size_t)bloc*(NH*LL) + h*LL + l)*LL + t0);
        float v0=bu2f(u.x), v1=bu2f(u.y), v2=bu2f(u.z), v3=bu2f(u.w);
        corr[h][t0]=v0; corr[h][t0+1]=v1; corr[h][t0+2]=v2; corr[h][t0+3]=v3;
        msum[0]+=v0; msum[1]+=v1; msum[2]+=v2; msum[3]+=v3;
    }
    #pragma unroll
    for(int j=0;j<4;j++) meanrow[t0+j] = msum[j]*0.125f;
    __syncthreads();
    int wv = tid >> 6, lane = tid & 63;
    #pragma unroll
    for(int hh=0; hh<2; hh++){
        int h = wv*2 + hh;
        float v[16];
        float mx = -1e30f;
        #pragma unroll
        for(int i=0;i<16;i++){
            int t = lane + 64*i;
            v[i] = corr[h][t] - meanrow[t];
            mx = fmaxf(mx, v[i]);
        }
        for(int off=32;off;off>>=1) mx = fmaxf(mx, __shfl_xor(mx, off, 64));
        float sm = 0.f;
        #pragma unroll
        for(int i=0;i<16;i++){ v[i] = __expf(v[i]-mx); sm += v[i]; }
        for(int off=32;off;off>>=1) sm += __shfl_xor(sm, off, 64);
        float inv = 1.f/sm;
        #pragma unroll
        for(int i=0;i<16;i++) corr[h][lane + 64*i] = v[i]*inv;
    }
    __syncthreads();
    #pragma unroll
    for(int h=0;h<NH;h++){
        ushort4v u;
        u.x = f2bu(corr[h][t0]);   u.y = f2bu(corr[h][t0+1]);
        u.z = f2bu(corr[h][t0+2]); u.w = f2bu(corr[h][t0+3]);
        *(ushort4v*)(W + ((size_t)bloc*(NH*LL) + h*LL + l)*LL + t0) = u;
    }
}

// MFMA pass2: Out[i,c] = sum_j W[j,i]*V[j,c] per (bloc,h); M=1024(i-tiles of 128),
// N=64(c), K=1024(j). LDS transpose staging: row stride 66 shorts (33 dwords == 1
// mod 32) -> packed-pair ds_write_b32 lands bank=lane%32 (conflict-free), frag
// reads via 4x b32 spread ~2-way (free). dst[b][c*8192 + h*1024 + i].
__global__ __launch_bounds__(256) void ac_pass2(const bf16* __restrict__ w,
                                                const bf16* __restrict__ v,
                                                bf16* __restrict__ dst,
                                                int b_off){
    __shared__ __align__(16) unsigned short As[128][66];  // [i][j]
    __shared__ __align__(16) unsigned short Bs[64][66];   // [c][j]
    int tid = threadIdx.x;
    int it = blockIdx.x, h = blockIdx.y, bloc = blockIdx.z;
    int b = b_off + bloc;
    int i0 = it*128;
    const unsigned short* wbase = (const unsigned short*)(w + ((size_t)(bloc*NH+h)*LL)*LL);
    const unsigned short* vbase = (const unsigned short*)(v + (size_t)b*LL*DD + h*DH);
    int wv = tid>>6, lane = tid&63;
    int wm = (wv>>1)*64, wn = (wv&1)*32;
    int rr = lane & 15, kb = (lane>>4)*8;
    floatx4 acc[4][2] = {};
    int iw = tid & 127, jqw = tid >> 7;    // W staging: i, j-quad group
    int cv = tid & 63,  jqv = tid >> 6;    // V staging: c, j-quad group
    for(int j0=0; j0<LL; j0+=64){
        #pragma unroll
        for(int p=0;p<8;p++){
            int jbase = (jqw + p*2)*4;
            unsigned short w0 = wbase[(size_t)(j0+jbase+0)*LL + i0 + iw];
            unsigned short w1 = wbase[(size_t)(j0+jbase+1)*LL + i0 + iw];
            unsigned short w2 = wbase[(size_t)(j0+jbase+2)*LL + i0 + iw];
            unsigned short w3 = wbase[(size_t)(j0+jbase+3)*LL + i0 + iw];
            unsigned* dp = (unsigned*)&As[iw][jbase];
            dp[0] = (unsigned)w0 | ((unsigned)w1 << 16);
            dp[1] = (unsigned)w2 | ((unsigned)w3 << 16);
        }
        #pragma unroll
        for(int p=0;p<4;p++){
            int jbase = (jqv + p*4)*4;
            unsigned short v0 = vbase[(size_t)(j0+jbase+0)*DD + cv];
            unsigned short v1 = vbase[(size_t)(j0+jbase+1)*DD + cv];
            unsigned short v2 = vbase[(size_t)(j0+jbase+2)*DD + cv];
            unsigned short v3 = vbase[(size_t)(j0+jbase+3)*DD + cv];
            unsigned* dp = (unsigned*)&Bs[cv][jbase];
            dp[0] = (unsigned)v0 | ((unsigned)v1 << 16);
            dp[1] = (unsigned)v2 | ((unsigned)v3 << 16);
        }
        __syncthreads();
        #pragma unroll
        for(int ks=0;ks<2;ks++){
            union { unsigned u[4]; short8 s; } fa[4], fb[2];
            #pragma unroll
            for(int mt=0;mt<4;mt++){
                const unsigned* ap = (const unsigned*)&As[wm+mt*16+rr][ks*32+kb];
                fa[mt].u[0]=ap[0]; fa[mt].u[1]=ap[1]; fa[mt].u[2]=ap[2]; fa[mt].u[3]=ap[3];
            }
            #pragma unroll
            for(int nt=0;nt<2;nt++){
                const unsigned* bp = (const unsigned*)&Bs[wn+nt*16+rr][ks*32+kb];
                fb[nt].u[0]=bp[0]; fb[nt].u[1]=bp[1]; fb[nt].u[2]=bp[2]; fb[nt].u[3]=bp[3];
            }
            #pragma unroll
            for(int mt=0;mt<4;mt++)
                #pragma unroll
                for(int nt=0;nt<2;nt++)
                    acc[mt][nt] = __builtin_amdgcn_mfma_f32_16x16x32_bf16(fa[mt].s, fb[nt].s, acc[mt][nt], 0,0,0);
        }
        __syncthreads();
    }
    bf16* db = dst + (size_t)b*LL*DD;
    int qrow = (lane>>4)*4, qcol = lane & 15;
    #pragma unroll
    for(int nt=0;nt<2;nt++){
        int c = wn + nt*16 + qcol;
        #pragma unroll
        for(int mt=0;mt<4;mt++){
            #pragma unroll
            for(int r=0;r<4;r++){
                int i = i0 + wm + mt*16 + qrow + r;
                db[(size_t)c*8192 + h*1024 + i] = f2b(acc[mt][nt][r]);
            }
        }
    }
}

// out = (seas + trend_sum) @ proj_w + proj_b  (dtype per flag)
__global__ __launch_bounds__(64) void final_kernel(const bf16* __restrict__ s,
                                                   const bf16* __restrict__ t,
                                                   const void* __restrict__ pwv,
                                                   const void* __restrict__ pbv,
                                                   const int* __restrict__ flag,
                                                   void* __restrict__ outv){
    bool f32 = (*flag != 0);
    int row = blockIdx.x;
    int lane = threadIdx.x;
    const bf16* sr = s + (size_t)row*DD;
    const bf16* tr = t + (size_t)row*DD;
    float acc[CO] = {};
    for(int j=lane; j<DD; j+=64){
        float dv = b2f(sr[j]) + b2f(tr[j]);
        if(f32){
            const float* pw = (const float*)pwv;
            #pragma unroll
            for(int c=0;c<CO;c++) acc[c] += dv * pw[j*CO + c];
        }else{
            const bf16* pw = (const bf16*)pwv;
            #pragma unroll
            for(int c=0;c<CO;c++) acc[c] += dv * b2f(pw[j*CO + c]);
        }
    }
    #pragma unroll
    for(int c=0;c<CO;c++){
        float vsum = acc[c];
        for(int off=32;off;off>>=1) vsum += __shfl_down(vsum,off,64);
        if(lane==0){
            float bias = f32 ? ((const float*)pbv)[c] : b2f(((const bf16*)pbv)[c]);
            float o = vsum + bias;
            if(f32) ((float*)outv)[(size_t)row*CO + c] = o;
            else    ((bf16*)outv)[(size_t)row*CO + c] = f2b(o);
        }
    }
}

extern "C" void kernel_launch(void* const* d_in, const int* in_sizes, int n_in,
                              void* d_out, int out_size, void* d_ws, size_t ws_size,
                              hipStream_t stream){
    const void* x_enc  = d_in[0];
    const void* x_dec  = d_in[2];
    const void* enc_w  = d_in[4];
    const void* enc_b  = d_in[5];
    const void* dec_w  = d_in[6];
    const void* dec_b  = d_in[7];
    const void* proj_w = d_in[8];
    const void* proj_b = d_in[9];

    int*  flag = (int*)d_ws;
    const size_t NE = (size_t)BB*LL*DD;
    bf16* A  = (bf16*)((char*)d_ws + 1024);
    bf16* Bf = A  + NE;
    bf16* C  = Bf + NE;
    bf16* T  = C  + NE;
    bf16* Tg = T  + NE;                          // 1024*64 bf16 trig table
    bf16* Ab = Tg + (size_t)LL*GK;               // per-batch spectra

    const size_t AB_ELEMS = (size_t)NH*LL*GK;
    const size_t W_ELEMS  = (size_t)NH*LL*LL;
    size_t base = 1024 + 4*NE*sizeof(bf16) + (size_t)LL*GK*sizeof(bf16);
    int bsz = 1;
    for(int cand : {8,4,2}){
        if(base + (size_t)cand*(AB_ELEMS + W_ELEMS)*sizeof(bf16) <= ws_size){ bsz = cand; break; }
    }
    bf16* W = Ab + (size_t)bsz*AB_ELEMS;

    sniff_kernel<<<1,64,0,stream>>>((const unsigned*)x_enc, flag);
    trig_init<<<LL,64,0,stream>>>(Tg);

    auto autocorr = [&](const bf16* q, const bf16* kv, bf16* dst){
        for(int b0 = 0; b0 < BB; b0 += bsz){
            dft_kernel<<<bsz*LL, 256, 0, stream>>>(q, kv, Ab, b0);
            corr_gemm<<<dim3(64, 8, bsz), 256, 0, stream>>>(Ab, Tg, W);
            softmax_kernel<<<bsz*LL, 256, 0, stream>>>(W);
            ac_pass2<<<dim3(8, NH, bsz), 256, 0, stream>>>(W, kv, dst, b0);
        }
    };

    embed_kernel<<<16384,256,0,stream>>>(x_enc, enc_w, enc_b, flag, Bf);
    decomp_kernel<<<16384,256,0,stream>>>(Bf, A, T, 0);   // A=enc_seasonal, T=enc_trend
    autocorr(A, A, Bf);      // layer 1 -> Bf
    autocorr(Bf, Bf, A);     // layer 2 -> A

    embed_kernel<<<16384,256,0,stream>>>(x_dec, dec_w, dec_b, flag, C);
    decomp_kernel<<<16384,256,0,stream>>>(C, Bf, T, 1);   // Bf=dec_seasonal, T+=dec_trend
    autocorr(Bf, A, C);      // cross layer -> C

    final_kernel<<<BB*LL,64,0,stream>>>(C, T, proj_w, proj_b, flag, d_out);
}

// Round 5
// 565.252 us; speedup vs baseline: 5.6026x; 1.0807x over previous
//
#include <hip/hip_runtime.h>
#include <hip/hip_bf16.h>

#define BB 8
#define LL 1024
#define DD 512
#define NH 8
#define DH 64
#define CO 7
#define GK 64          // K for corr GEMM: f=1..32, (re,im) pairs; f=0 dropped (softmax-invariant)

typedef __hip_bfloat16 bf16;
typedef __attribute__((ext_vector_type(8))) short short8;
typedef __attribute__((ext_vector_type(4))) float floatx4;

__device__ __forceinline__ float b2f(bf16 v){ return __bfloat162float(v); }
__device__ __forceinline__ bf16 f2b(float v){ return __float2bfloat16(v); }

// Decide whether global float data is genuine f32 (flag=1) or packed bf16 (flag=0).
__global__ void sniff_kernel(const unsigned* __restrict__ x, int* __restrict__ flag){
    unsigned u = x[threadIdx.x];
    int e = (u >> 23) & 0xff;
    int sane = (e >= 32 && e <= 200) ? 1 : 0;
    unsigned long long m = __ballot(sane);
    if(threadIdx.x == 0) *flag = (__popcll(m) >= 32) ? 1 : 0;
}

// moving average over the 7-channel input: xm = MA25(x), xs = x - xm  (f32 out)
// MA commutes with the linear embed, so decomp happens pre-embedding (7 ch, not 512).
__global__ __launch_bounds__(256) void ma7_kernel(const void* __restrict__ xv,
                                                  const int* __restrict__ flag,
                                                  float* __restrict__ xs,
                                                  float* __restrict__ xm){
    int idx = blockIdx.x*256 + threadIdx.x;
    if(idx >= BB*LL*7) return;
    bool f32 = (*flag != 0);
    int i = idx % 7;
    int row = idx / 7;              // b*L + l
    int l = row & (LL-1);
    int b = row >> 10;
    int lo = l-12; if(lo<0) lo=0;
    int hi = l+12; if(hi>LL-1) hi=LL-1;
    float s = 0.f, xc;
    if(f32){
        const float* x = (const float*)xv + ((size_t)b*LL)*7 + i;
        for(int m=lo;m<=hi;m++) s += x[(size_t)m*7];
        xc = x[(size_t)l*7];
    }else{
        const bf16* x = (const bf16*)xv + ((size_t)b*LL)*7 + i;
        for(int m=lo;m<=hi;m++) s += b2f(x[(size_t)m*7]);
        xc = b2f(x[(size_t)l*7]);
    }
    float ma = s*(1.f/25.f);
    xm[idx] = ma;
    xs[idx] = xc - ma;
}

// seas[b,l,d] = xs@W + bias*(1-cnt/25); trend = xm@W + bias*cnt/25 (+= if accumulate)
__global__ __launch_bounds__(256) void embed2_kernel(const float* __restrict__ xs,
                                                     const float* __restrict__ xm,
                                                     const void* __restrict__ wv,
                                                     const void* __restrict__ bv,
                                                     const int* __restrict__ flag,
                                                     bf16* __restrict__ seas,
                                                     bf16* __restrict__ trend,
                                                     int accumulate){
    bool f32 = (*flag != 0);
    int idx = blockIdx.x*256 + threadIdx.x;
    int d = idx & (DD-1);
    int row = idx >> 9;
    int l = row & (LL-1);
    int lo = l-12; if(lo<0) lo=0;
    int hi = l+12; if(hi>LL-1) hi=LL-1;
    float cf = (float)(hi-lo+1) * (1.f/25.f);
    float wcol[7], bias;
    if(f32){
        const float* w = (const float*)wv;
        #pragma unroll
        for(int i=0;i<7;i++) wcol[i] = w[i*DD + d];
        bias = ((const float*)bv)[d];
    }else{
        const bf16* w = (const bf16*)wv;
        #pragma unroll
        for(int i=0;i<7;i++) wcol[i] = b2f(w[i*DD + d]);
        bias = b2f(((const bf16*)bv)[d]);
    }
    float sa = 0.f, ta = 0.f;
    #pragma unroll
    for(int i=0;i<7;i++){
        sa += xs[row*7+i]*wcol[i];
        ta += xm[row*7+i]*wcol[i];
    }
    seas[idx] = f2b(sa + bias*(1.f-cf));
    float t = ta + bias*cf;
    if(accumulate) t += b2f(trend[idx]);
    trend[idx] = f2b(t);
}

// trig table Tg[t][k]: k=2(f-1) -> cos(2*pi*f*t/1024), k=2(f-1)+1 -> sin, f=1..32
__global__ __launch_bounds__(64) void trig_init(bf16* __restrict__ Tg){
    int t = blockIdx.x, k = threadIdx.x;
    int f = (k >> 1) + 1;
    int ph = (f*t) & 1023;
    float s, c;
    __sincosf((float)ph * (6.28318530717958647692f/1024.f), &s, &c);
    Tg[(size_t)t*GK + k] = f2b((k & 1) ? s : c);
}

// Per (b,l): 64-pt DFT per head of q-row and k-row, C_f = qf*conj(kf), f=1..32;
// subtract cross-head mean (linear in A => softmax mean-subtract moves here);
// A[m=h*1024+l][2(f-1)]=Re*s, [2(f-1)+1]=-Im*s.
__global__ __launch_bounds__(256) void dft_kernel(const bf16* __restrict__ q,
                                                  const bf16* __restrict__ k,
                                                  bf16* __restrict__ Ab,
                                                  int b_off){
    __shared__ float qr[DD], kr[DD];
    __shared__ float mre[NH][32], mim[NH][32];
    int tid = threadIdx.x;
    int bloc = blockIdx.x >> 10;
    int b = b_off + bloc;
    int l = blockIdx.x & (LL-1);
    const bf16* qrow = q + ((size_t)b*LL + l)*DD;
    const bf16* krow = k + ((size_t)b*LL + l)*DD;
    qr[tid] = b2f(qrow[tid]); qr[tid+256] = b2f(qrow[tid+256]);
    kr[tid] = b2f(krow[tid]); kr[tid+256] = b2f(krow[tid+256]);
    __syncthreads();
    int h = tid >> 5, fi = tid & 31, f = fi + 1;
    const float* qh = qr + h*DH;
    const float* kh = kr + h*DH;
    float sb, cb;
    __sincosf((float)f * (6.28318530717958647692f/64.f), &sb, &cb);
    float cr = 1.f, ci = 0.f;   // e^{-i*2*pi*f*j/64}
    float qre=0.f,qim=0.f,kre=0.f,kim=0.f;
    for(int j=0;j<DH;j++){
        float qv = qh[j], kv = kh[j];
        qre += qv*cr; qim += qv*ci;
        kre += kv*cr; kim += kv*ci;
        float nr = cr*cb + ci*sb;
        float ni = ci*cb - cr*sb;
        cr = nr; ci = ni;
    }
    const float scale = 1.f/512.f;            // 2/1024
    float re = (qre*kre + qim*kim)*scale;
    float im = -(qim*kre - qre*kim)*scale;
    mre[h][fi] = re; mim[h][fi] = im;
    __syncthreads();
    float sre = 0.f, sim = 0.f;
    #pragma unroll
    for(int hh=0; hh<NH; hh++){ sre += mre[hh][fi]; sim += mim[hh][fi]; }
    re -= sre*0.125f; im -= sim*0.125f;
    size_t rowb = ((size_t)bloc*(NH*LL) + h*LL + l)*GK;
    Ab[rowb + 2*fi]   = f2b(re);
    Ab[rowb + 2*fi+1] = f2b(im);
}

// Fused corr GEMM + softmax: block computes 16 m-rows x 1024 t (K=64),
// then per-row softmax in registers; writes softmaxed bf16 W once.
__global__ __launch_bounds__(256) void corr_softmax(const bf16* __restrict__ Ab,
                                                    const bf16* __restrict__ Tg,
                                                    bf16* __restrict__ Wb){
    __shared__ float redmx[4][16];
    __shared__ float redsm[4][16];
    int tid = threadIdx.x, wv = tid >> 6, lane = tid & 63;
    int m0 = blockIdx.x * 16;             // row within bloc's 8192
    int bloc = blockIdx.y;
    int rr = lane & 15, kb = (lane>>4)*8;
    int rg = (lane>>4)*4;                 // this lane's base C/D row
    int t0 = wv*256;
    const short* Abase = (const short*)(Ab + ((size_t)bloc*(NH*LL))*GK);
    const short* Tb = (const short*)Tg;
    short8 af0 = *(const short8*)&Abase[(size_t)(m0+rr)*GK + kb];
    short8 af1 = *(const short8*)&Abase[(size_t)(m0+rr)*GK + 32 + kb];
    floatx4 acc[16];
    #pragma unroll
    for(int nt=0;nt<16;nt++){
        short8 b0 = *(const short8*)&Tb[(size_t)(t0+nt*16+rr)*GK + kb];
        short8 b1 = *(const short8*)&Tb[(size_t)(t0+nt*16+rr)*GK + 32 + kb];
        floatx4 a = {};
        a = __builtin_amdgcn_mfma_f32_16x16x32_bf16(af0, b0, a, 0,0,0);
        a = __builtin_amdgcn_mfma_f32_16x16x32_bf16(af1, b1, a, 0,0,0);
        acc[nt] = a;
    }
    // per-row max across this wave's 256 cols
    float mx[4] = {-1e30f,-1e30f,-1e30f,-1e30f};
    #pragma unroll
    for(int nt=0;nt<16;nt++)
        #pragma unroll
        for(int r=0;r<4;r++) mx[r] = fmaxf(mx[r], acc[nt][r]);
    #pragma unroll
    for(int o=1;o<16;o<<=1)
        #pragma unroll
        for(int r=0;r<4;r++) mx[r] = fmaxf(mx[r], __shfl_xor(mx[r], o, 16));
    if(rr == 0){
        #pragma unroll
        for(int r=0;r<4;r++) redmx[wv][rg+r] = mx[r];
    }
    __syncthreads();
    #pragma unroll
    for(int r=0;r<4;r++)
        mx[r] = fmaxf(fmaxf(redmx[0][rg+r], redmx[1][rg+r]),
                      fmaxf(redmx[2][rg+r], redmx[3][rg+r]));
    // exp + row sum
    float sm[4] = {};
    #pragma unroll
    for(int nt=0;nt<16;nt++)
        #pragma unroll
        for(int r=0;r<4;r++){
            float e = __expf(acc[nt][r] - mx[r]);
            acc[nt][r] = e; sm[r] += e;
        }
    #pragma unroll
    for(int o=1;o<16;o<<=1)
        #pragma unroll
        for(int r=0;r<4;r++) sm[r] += __shfl_xor(sm[r], o, 16);
    if(rr == 0){
        #pragma unroll
        for(int r=0;r<4;r++) redsm[wv][rg+r] = sm[r];
    }
    __syncthreads();
    float inv[4];
    #pragma unroll
    for(int r=0;r<4;r++)
        inv[r] = 1.f/(redsm[0][rg+r]+redsm[1][rg+r]+redsm[2][rg+r]+redsm[3][rg+r]);
    bf16* wbase = Wb + ((size_t)bloc*(NH*LL) + m0)*LL + t0;
    #pragma unroll
    for(int nt=0;nt<16;nt++)
        #pragma unroll
        for(int r=0;r<4;r++)
            wbase[(size_t)(rg+r)*LL + nt*16 + rr] = f2b(acc[nt][r]*inv[r]);
}

// MFMA pass2: Out[i,c] = sum_j W[j,i]*V[j,c] per (bloc,h); dst[b][c*8192+h*1024+i]
__global__ __launch_bounds__(256) void ac_pass2(const bf16* __restrict__ w,
                                                const bf16* __restrict__ v,
                                                bf16* __restrict__ dst,
                                                int b_off){
    __shared__ __align__(16) unsigned short As[128][66];  // [i][j]
    __shared__ __align__(16) unsigned short Bs[64][66];   // [c][j]
    int tid = threadIdx.x;
    int it = blockIdx.x, h = blockIdx.y, bloc = blockIdx.z;
    int b = b_off + bloc;
    int i0 = it*128;
    const unsigned short* wbase = (const unsigned short*)(w + ((size_t)(bloc*NH+h)*LL)*LL);
    const unsigned short* vbase = (const unsigned short*)(v + (size_t)b*LL*DD + h*DH);
    int wv = tid>>6, lane = tid&63;
    int wm = (wv>>1)*64, wn = (wv&1)*32;
    int rr = lane & 15, kb = (lane>>4)*8;
    floatx4 acc[4][2] = {};
    int iw = tid & 127, jqw = tid >> 7;
    int cv = tid & 63,  jqv = tid >> 6;
    for(int j0=0; j0<LL; j0+=64){
        #pragma unroll
        for(int p=0;p<8;p++){
            int jbase = (jqw + p*2)*4;
            unsigned short w0 = wbase[(size_t)(j0+jbase+0)*LL + i0 + iw];
            unsigned short w1 = wbase[(size_t)(j0+jbase+1)*LL + i0 + iw];
            unsigned short w2 = wbase[(size_t)(j0+jbase+2)*LL + i0 + iw];
            unsigned short w3 = wbase[(size_t)(j0+jbase+3)*LL + i0 + iw];
            unsigned* dp = (unsigned*)&As[iw][jbase];
            dp[0] = (unsigned)w0 | ((unsigned)w1 << 16);
            dp[1] = (unsigned)w2 | ((unsigned)w3 << 16);
        }
        #pragma unroll
        for(int p=0;p<4;p++){
            int jbase = (jqv + p*4)*4;
            unsigned short v0 = vbase[(size_t)(j0+jbase+0)*DD + cv];
            unsigned short v1 = vbase[(size_t)(j0+jbase+1)*DD + cv];
            unsigned short v2 = vbase[(size_t)(j0+jbase+2)*DD + cv];
            unsigned short v3 = vbase[(size_t)(j0+jbase+3)*DD + cv];
            unsigned* dp = (unsigned*)&Bs[cv][jbase];
            dp[0] = (unsigned)v0 | ((unsigned)v1 << 16);
            dp[1] = (unsigned)v2 | ((unsigned)v3 << 16);
        }
        __syncthreads();
        #pragma unroll
        for(int ks=0;ks<2;ks++){
            union { unsigned u[4]; short8 s; } fa[4], fb[2];
            #pragma unroll
            for(int mt=0;mt<4;mt++){
                const unsigned* ap = (const unsigned*)&As[wm+mt*16+rr][ks*32+kb];
                fa[mt].u[0]=ap[0]; fa[mt].u[1]=ap[1]; fa[mt].u[2]=ap[2]; fa[mt].u[3]=ap[3];
            }
            #pragma unroll
            for(int nt=0;nt<2;nt++){
                const unsigned* bp = (const unsigned*)&Bs[wn+nt*16+rr][ks*32+kb];
                fb[nt].u[0]=bp[0]; fb[nt].u[1]=bp[1]; fb[nt].u[2]=bp[2]; fb[nt].u[3]=bp[3];
            }
            #pragma unroll
            for(int mt=0;mt<4;mt++)
                #pragma unroll
                for(int nt=0;nt<2;nt++)
                    acc[mt][nt] = __builtin_amdgcn_mfma_f32_16x16x32_bf16(fa[mt].s, fb[nt].s, acc[mt][nt], 0,0,0);
        }
        __syncthreads();
    }
    bf16* db = dst + (size_t)b*LL*DD;
    int qrow = (lane>>4)*4, qcol = lane & 15;
    #pragma unroll
    for(int nt=0;nt<2;nt++){
        int c = wn + nt*16 + qcol;
        #pragma unroll
        for(int mt=0;mt<4;mt++){
            #pragma unroll
            for(int r=0;r<4;r++){
                int i = i0 + wm + mt*16 + qrow + r;
                db[(size_t)c*8192 + h*1024 + i] = f2b(acc[mt][nt][r]);
            }
        }
    }
}

// out = (seas + trend_sum) @ proj_w + proj_b  (dtype per flag)
__global__ __launch_bounds__(64) void final_kernel(const bf16* __restrict__ s,
                                                   const bf16* __restrict__ t,
                                                   const void* __restrict__ pwv,
                                                   const void* __restrict__ pbv,
                                                   const int* __restrict__ flag,
                                                   void* __restrict__ outv){
    bool f32 = (*flag != 0);
    int row = blockIdx.x;
    int lane = threadIdx.x;
    const bf16* sr = s + (size_t)row*DD;
    const bf16* tr = t + (size_t)row*DD;
    float acc[CO] = {};
    for(int j=lane; j<DD; j+=64){
        float dv = b2f(sr[j]) + b2f(tr[j]);
        if(f32){
            const float* pw = (const float*)pwv;
            #pragma unroll
            for(int c=0;c<CO;c++) acc[c] += dv * pw[j*CO + c];
        }else{
            const bf16* pw = (const bf16*)pwv;
            #pragma unroll
            for(int c=0;c<CO;c++) acc[c] += dv * b2f(pw[j*CO + c]);
        }
    }
    #pragma unroll
    for(int c=0;c<CO;c++){
        float vsum = acc[c];
        for(int off=32;off;off>>=1) vsum += __shfl_down(vsum,off,64);
        if(lane==0){
            float bias = f32 ? ((const float*)pbv)[c] : b2f(((const bf16*)pbv)[c]);
            float o = vsum + bias;
            if(f32) ((float*)outv)[(size_t)row*CO + c] = o;
            else    ((bf16*)outv)[(size_t)row*CO + c] = f2b(o);
        }
    }
}

extern "C" void kernel_launch(void* const* d_in, const int* in_sizes, int n_in,
                              void* d_out, int out_size, void* d_ws, size_t ws_size,
                              hipStream_t stream){
    const void* x_enc  = d_in[0];
    const void* x_dec  = d_in[2];
    const void* enc_w  = d_in[4];
    const void* enc_b  = d_in[5];
    const void* dec_w  = d_in[6];
    const void* dec_b  = d_in[7];
    const void* proj_w = d_in[8];
    const void* proj_b = d_in[9];

    int*  flag = (int*)d_ws;
    const size_t NE = (size_t)BB*LL*DD;
    bf16* A  = (bf16*)((char*)d_ws + 1024);
    bf16* Bf = A  + NE;
    bf16* C  = Bf + NE;
    bf16* T  = C  + NE;
    bf16* Tg = T  + NE;                          // 1024*64 bf16 trig table
    float* xs = (float*)(Tg + (size_t)LL*GK);    // [B,L,7] f32
    float* xm = xs + (size_t)BB*LL*7;
    bf16* Ab  = (bf16*)(xm + (size_t)BB*LL*7);

    const size_t AB_ELEMS = (size_t)NH*LL*GK;
    const size_t W_ELEMS  = (size_t)NH*LL*LL;
    size_t base = (size_t)((char*)Ab - (char*)d_ws);
    int bsz = 1;
    for(int cand : {8,4,2}){
        if(base + (size_t)cand*(AB_ELEMS + W_ELEMS)*sizeof(bf16) <= ws_size){ bsz = cand; break; }
    }
    bf16* W = Ab + (size_t)bsz*AB_ELEMS;

    sniff_kernel<<<1,64,0,stream>>>((const unsigned*)x_enc, flag);
    trig_init<<<LL,64,0,stream>>>(Tg);

    auto autocorr = [&](const bf16* q, const bf16* kv, bf16* dst){
        for(int b0 = 0; b0 < BB; b0 += bsz){
            dft_kernel<<<bsz*LL, 256, 0, stream>>>(q, kv, Ab, b0);
            corr_softmax<<<dim3(512, bsz), 256, 0, stream>>>(Ab, Tg, W);
            ac_pass2<<<dim3(8, NH, bsz), 256, 0, stream>>>(W, kv, dst, b0);
        }
    };

    const int MA_GRID = (BB*LL*7 + 255)/256;
    // encoder: MA(x) -> fused embed+decomp -> 2x self-autocorr
    ma7_kernel<<<MA_GRID,256,0,stream>>>(x_enc, flag, xs, xm);
    embed2_kernel<<<16384,256,0,stream>>>(xs, xm, enc_w, enc_b, flag, A, T, 0);
    autocorr(A, A, Bf);      // layer 1 -> Bf
    autocorr(Bf, Bf, A);     // layer 2 -> A (= enc_seasonal out)

    // decoder: MA(x_dec) -> fused embed+decomp (trend accumulates) -> cross autocorr
    ma7_kernel<<<MA_GRID,256,0,stream>>>(x_dec, flag, xs, xm);
    embed2_kernel<<<16384,256,0,stream>>>(xs, xm, dec_w, dec_b, flag, Bf, T, 1);
    autocorr(Bf, A, C);      // cross layer -> C

    final_kernel<<<BB*LL,64,0,stream>>>(C, T, proj_w, proj_b, flag, d_out);
}